// Round 5
// baseline (917.587 us; speedup 1.0000x reference)
//
#include <hip/hip_runtime.h>

#define ND 64
#define NPAIR 6

typedef short bf16x8 __attribute__((ext_vector_type(8)));
typedef float floatx4 __attribute__((ext_vector_type(4)));

static constexpr int SPB  = 8;             // samples per group
static constexpr int ROWS = SPB * NPAIR;   // 48 rows = 3 waves x 16 (B-operand n-cols)
static constexpr int GRP  = 8;             // groups per persistent block

__device__ __forceinline__ unsigned short f2bf(float f) {
    unsigned u = __builtin_bit_cast(unsigned, f);
    u += 0x7FFFu + ((u >> 16) & 1u);       // RNE (no NaN inputs)
    return (unsigned short)(u >> 16);
}
__device__ __forceinline__ unsigned f2bf2(float lo, float hi) {
    return (unsigned)f2bf(lo) | ((unsigned)f2bf(hi) << 16);
}
__device__ __forceinline__ unsigned relupack2(float a, float ba, float b, float bb) {
    float u = a + ba; u = u > 0.f ? u : 0.f;
    float v = b + bb; v = v > 0.f ? v : 0.f;
    return f2bf2(u, v);
}
// XOR chunk swizzles (chunk = 8 halfwords = 16B) — verified conflict reduction R3/R4
__device__ __forceinline__ int swzAx(int row, int c) { return (c & 8) | ((c ^ row) & 7); } // c 0..15
__device__ __forceinline__ int swzD (int row, int c) { return (c ^ row) & 7; }             // c 0..7

// Repack W1..3 into A-operand fragments for D = W*Act with channel permutation
// pi(ot,m) = 32*(ot>>1) + 8*(m>>2) + 4*(ot&1) + (m&3)  (m = quad*4+reg of C-layout)
// Layout: P[(((L*4+ot)*6 + c)*64 + lane)*8 + j]; lane=(q*16+m): element k = c*32 + q*8 + j
__global__ void repack_w(const float* __restrict__ W1, const float* __restrict__ W2,
                         const float* __restrict__ W3, unsigned short* __restrict__ P) {
    int idx = blockIdx.x * 256 + threadIdx.x;
    if (idx >= 3 * 4 * 6 * 64 * 8) return;   // 36864
    int j    = idx & 7;
    int lane = (idx >> 3) & 63;
    int g    = idx >> 9;                     // (L*4+ot)*6 + c
    int c    = g % 6;
    int ot   = (g / 6) & 3;
    int L    = g / 24;
    int m = lane & 15, q = lane >> 4;
    int ch = 32 * (ot >> 1) + 8 * (m >> 2) + 4 * (ot & 1) + (m & 3);
    int k  = c * 32 + q * 8 + j;
    const float* W = (L == 0) ? W1 : (L == 1) ? W2 : W3;
    float v = (k < 128) ? W[ch * 192 + (k >> 1) * 3 + (k & 1)]
                        : W[ch * 192 + (k - 128) * 3 + 2];
    P[idx] = f2bf(v);
}

// Persistent: 1024 blocks x 3 waves; each block pipelines GRP=8 consecutive groups.
// While group g computes its 3 in-register layers, g+1's global loads drain into regs
// and its convert+scatter runs; g+2's loads issue after the regs are consumed.
__global__ __launch_bounds__(192, 3) void dijet_main(
    const float* __restrict__ x, const float* __restrict__ d,
    const float* __restrict__ b1, const float* __restrict__ b2,
    const float* __restrict__ b3, const unsigned short* __restrict__ Wa,
    float* __restrict__ out)
{
    __shared__ __align__(16) unsigned short Xs[ROWS * 128];  // 12288 B, swizzled x-part
    __shared__ __align__(16) unsigned short Ds[ROWS * 64];   //  6144 B, swizzled d-part
    __shared__ __align__(16) float Co[SPB * 390];            // 12480 B, out transpose (+6 pad/sample)

    const int t    = threadIdx.x;          // 0..191
    const int wv   = t >> 6;
    const int lane = t & 63;
    const int l15  = lane & 15;
    const int q    = lane >> 4;

    // staging index constants (R4-verified mapping)
    const int i_d = t / 3;                       // channel 0..63
    const int s_d = 2 * (t - 3 * (t / 3));       // slot 0,2,4
    const int c16 = i_d >> 2;                    // 16B chunk of j=2i
    const int iw  = i_d & 3;
    const int r   = wv * 16 + l15;               // lane's sample-row (n-col)
    const int rb  = r / 6, rs = r - 6 * rb;

    const size_t gbase = (size_t)blockIdx.x * (GRP * SPB);
    const float2* d2 = (const float2*)(d + gbase * 384);
    const float4* x4 = (const float4*)(x + gbase * 768);
    float2* out2 = (float2*)(out + gbase * 384);

    float2 dnx[8];
    float4 xnx[8];
    float2 dres[8];
    bf16x8 Bx[4], Bd0g, Bd1g;

    // ---- prologue: load group 0, scatter, gather; then issue group 1 loads
    #pragma unroll
    for (int m = 0; m < 8; ++m) { dnx[m] = d2[m * 192 + t]; xnx[m] = x4[m * 192 + t]; }
    {
        unsigned* Xs32 = (unsigned*)Xs;
        #pragma unroll
        for (int m = 0; m < 8; ++m) {
            int row0 = m * 6 + s_d, row1 = row0 + 1;
            Xs32[row0 * 64 + swzAx(row0, c16) * 4 + iw] = f2bf2(xnx[m].x, xnx[m].y);
            Xs32[row1 * 64 + swzAx(row1, c16) * 4 + iw] = f2bf2(xnx[m].z, xnx[m].w);
            Ds[row0 * 64 + swzD(row0, i_d >> 3) * 8 + (i_d & 7)] = f2bf(dnx[m].x);
            Ds[row1 * 64 + swzD(row1, i_d >> 3) * 8 + (i_d & 7)] = f2bf(dnx[m].y);
        }
    }
    __syncthreads();
    #pragma unroll
    for (int kk = 0; kk < 4; ++kk)
        Bx[kk] = *(const bf16x8*)(Xs + r * 128 + swzAx(r, kk * 4 + q) * 8);
    Bd0g = *(const bf16x8*)(Ds + r * 64 + swzD(r, q) * 8);
    Bd1g = *(const bf16x8*)(Ds + r * 64 + swzD(r, 4 + q) * 8);
    __syncthreads();
    #pragma unroll
    for (int m = 0; m < 8; ++m) dres[m] = dnx[m];
    #pragma unroll
    for (int m = 0; m < 8; ++m) { dnx[m] = d2[1536 + m * 192 + t]; xnx[m] = x4[1536 + m * 192 + t]; }

    #pragma unroll 1
    for (int it = 0; it < GRP; ++it) {
        // ---- 3 in-register layers for group `it` (zero LDS, zero barriers)
        bf16x8 Bd0 = Bd0g, Bd1 = Bd1g;
        floatx4 acc[4];
        float4 bl0f, bl1f, bh0f, bh1f;
        #pragma unroll
        for (int L = 0; L < 3; ++L) {
            const float* bL = (L == 0) ? b1 : (L == 1) ? b2 : b3;
            const unsigned short* WL = Wa + L * 12288 + lane * 8;
            #pragma unroll
            for (int ot = 0; ot < 4; ++ot) {
                const unsigned short* wt = WL + ot * 3072;
                floatx4 a = {0.f, 0.f, 0.f, 0.f};
                a = __builtin_amdgcn_mfma_f32_16x16x32_bf16(*(const bf16x8*)(wt),        Bx[0], a, 0, 0, 0);
                a = __builtin_amdgcn_mfma_f32_16x16x32_bf16(*(const bf16x8*)(wt + 512),  Bx[1], a, 0, 0, 0);
                a = __builtin_amdgcn_mfma_f32_16x16x32_bf16(*(const bf16x8*)(wt + 1024), Bx[2], a, 0, 0, 0);
                a = __builtin_amdgcn_mfma_f32_16x16x32_bf16(*(const bf16x8*)(wt + 1536), Bx[3], a, 0, 0, 0);
                a = __builtin_amdgcn_mfma_f32_16x16x32_bf16(*(const bf16x8*)(wt + 2048), Bd0,   a, 0, 0, 0);
                a = __builtin_amdgcn_mfma_f32_16x16x32_bf16(*(const bf16x8*)(wt + 2560), Bd1,   a, 0, 0, 0);
                acc[ot] = a;
            }
            const float4* bv4 = (const float4*)bL;
            const float4 bl0 = bv4[2 * q],     bl1 = bv4[2 * q + 1];
            const float4 bh0 = bv4[8 + 2 * q], bh1 = bv4[8 + 2 * q + 1];
            if (L < 2) {
                union { bf16x8 h; unsigned u[4]; } p0, p1;
                p0.u[0] = relupack2(acc[0][0], bl0.x, acc[0][1], bl0.y);
                p0.u[1] = relupack2(acc[0][2], bl0.z, acc[0][3], bl0.w);
                p0.u[2] = relupack2(acc[1][0], bl1.x, acc[1][1], bl1.y);
                p0.u[3] = relupack2(acc[1][2], bl1.z, acc[1][3], bl1.w);
                p1.u[0] = relupack2(acc[2][0], bh0.x, acc[2][1], bh0.y);
                p1.u[1] = relupack2(acc[2][2], bh0.z, acc[2][3], bh0.w);
                p1.u[2] = relupack2(acc[3][0], bh1.x, acc[3][1], bh1.y);
                p1.u[3] = relupack2(acc[3][2], bh1.z, acc[3][3], bh1.w);
                Bd0 = p0.h; Bd1 = p1.h;
            } else {
                bl0f = bl0; bl1f = bl1; bh0f = bh0; bh1f = bh1;
            }
        }

        // ---- scatter group it+1 (overlaps with the above in scheduler; loads issued last iter)
        if (it + 1 < GRP) {
            unsigned* Xs32 = (unsigned*)Xs;
            #pragma unroll
            for (int m = 0; m < 8; ++m) {
                int row0 = m * 6 + s_d, row1 = row0 + 1;
                Xs32[row0 * 64 + swzAx(row0, c16) * 4 + iw] = f2bf2(xnx[m].x, xnx[m].y);
                Xs32[row1 * 64 + swzAx(row1, c16) * 4 + iw] = f2bf2(xnx[m].z, xnx[m].w);
                Ds[row0 * 64 + swzD(row0, i_d >> 3) * 8 + (i_d & 7)] = f2bf(dnx[m].x);
                Ds[row1 * 64 + swzD(row1, i_d >> 3) * 8 + (i_d & 7)] = f2bf(dnx[m].y);
            }
        }

        // ---- Co write for group it (fp32 + bias, transpose to [b][ch*6+s], stride 390)
        {
            float* cb = Co + rb * 390 + rs + (8 * q) * 6;
            cb[0]   = acc[0][0] + bl0f.x; cb[6]   = acc[0][1] + bl0f.y;
            cb[12]  = acc[0][2] + bl0f.z; cb[18]  = acc[0][3] + bl0f.w;
            cb[24]  = acc[1][0] + bl1f.x; cb[30]  = acc[1][1] + bl1f.y;
            cb[36]  = acc[1][2] + bl1f.z; cb[42]  = acc[1][3] + bl1f.w;
            cb[192] = acc[2][0] + bh0f.x; cb[198] = acc[2][1] + bh0f.y;
            cb[204] = acc[2][2] + bh0f.z; cb[210] = acc[2][3] + bh0f.w;
            cb[216] = acc[3][0] + bh1f.x; cb[222] = acc[3][1] + bh1f.y;
            cb[228] = acc[3][2] + bh1f.z; cb[234] = acc[3][3] + bh1f.w;
        }
        __syncthreads();   // B1: Co writes + it+1 scatter visible

        // ---- coalesced out store for group it, fused with fp32 residual + final relu
        #pragma unroll
        for (int m = 0; m < 8; ++m) {
            float2 c = *(const float2*)(Co + m * 390 + 2 * t);
            float2 rv;
            rv.x = c.x + dres[m].x; rv.x = rv.x > 0.f ? rv.x : 0.f;
            rv.y = c.y + dres[m].y; rv.y = rv.y > 0.f ? rv.y : 0.f;
            out2[it * 1536 + m * 192 + t] = rv;
        }

        // ---- gather it+1 frags; rotate residual regs; issue it+2 loads
        if (it + 1 < GRP) {
            #pragma unroll
            for (int kk = 0; kk < 4; ++kk)
                Bx[kk] = *(const bf16x8*)(Xs + r * 128 + swzAx(r, kk * 4 + q) * 8);
            Bd0g = *(const bf16x8*)(Ds + r * 64 + swzD(r, q) * 8);
            Bd1g = *(const bf16x8*)(Ds + r * 64 + swzD(r, 4 + q) * 8);
            #pragma unroll
            for (int m = 0; m < 8; ++m) dres[m] = dnx[m];
            if (it + 2 < GRP) {
                #pragma unroll
                for (int m = 0; m < 8; ++m) {
                    dnx[m] = d2[(it + 2) * 1536 + m * 192 + t];
                    xnx[m] = x4[(it + 2) * 1536 + m * 192 + t];
                }
            }
        }
        __syncthreads();   // B2: gathers + Co reads done -> next iter may scatter/Co-write
    }
}

extern "C" void kernel_launch(void* const* d_in, const int* in_sizes, int n_in,
                              void* d_out, int out_size, void* d_ws, size_t ws_size,
                              hipStream_t stream)
{
    const float* x  = (const float*)d_in[0];
    const float* dd = (const float*)d_in[1];
    const float* W1 = (const float*)d_in[2];
    const float* b1 = (const float*)d_in[3];
    const float* W2 = (const float*)d_in[4];
    const float* b2 = (const float*)d_in[5];
    const float* W3 = (const float*)d_in[6];
    const float* b3 = (const float*)d_in[7];
    float* out = (float*)d_out;
    unsigned short* Wp = (unsigned short*)d_ws;   // 3*4*6*64*8*2 = 73728 B

    int n = in_sizes[0] / (ND * 12);              // 65536

    repack_w<<<144, 256, 0, stream>>>(W1, W2, W3, Wp);
    dijet_main<<<n / (SPB * GRP), 192, 0, stream>>>(x, dd, b1, b2, b3, Wp, out);
}

// Round 6
// 390.605 us; speedup vs baseline: 2.3491x; 2.3491x over previous
//
#include <hip/hip_runtime.h>

#define ND 64
#define NPAIR 6

typedef short bf16x8 __attribute__((ext_vector_type(8)));
typedef float floatx4 __attribute__((ext_vector_type(4)));

static constexpr int SPB  = 8;             // samples per block
static constexpr int ROWS = SPB * NPAIR;   // 48 M-rows per block
static constexpr int ASTR = 200;           // halfwords per A row (192 + 8 pad; 400B, 16B-aligned, bank-spread)

// Native bf16 conversion: compiler emits v_cvt_pk_bf16_f32 (RNE) for scalar casts
// on gfx950 — measured faster than hand-rolled bit-twiddle AND than inline asm (m240).
__device__ __forceinline__ unsigned short f2bf(float f) {
    __bf16 h = (__bf16)f;
    return __builtin_bit_cast(unsigned short, h);
}
__device__ __forceinline__ unsigned f2bf2(float lo, float hi) {
    return (unsigned)f2bf(lo) | ((unsigned)f2bf(hi) << 16);
}

// Repack W1..3 [o][i][k] fp32 -> bf16 B-operand layout P[L][n=o][j], j<128: (i=j>>1,k=j&1), j>=128: (i=j-128,k=2)
__global__ void repack_w(const float* __restrict__ W1, const float* __restrict__ W2,
                         const float* __restrict__ W3, unsigned short* __restrict__ P) {
    int idx = blockIdx.x * 256 + threadIdx.x;
    if (idx >= 3 * 64 * 192) return;
    int j = idx % 192;
    int n = (idx / 192) % 64;
    int L = idx / (192 * 64);
    const float* W = (L == 0) ? W1 : (L == 1) ? W2 : W3;
    float v = (j < 128) ? W[n * 192 + (j >> 1) * 3 + (j & 1)]
                        : W[n * 192 + (j - 128) * 3 + 2];
    P[idx] = f2bf(v);
}

__global__ __launch_bounds__(256, 7) void dijet_main(
    const float* __restrict__ x, const float* __restrict__ d,
    const float* __restrict__ b1, const float* __restrict__ b2,
    const float* __restrict__ b3, const unsigned short* __restrict__ Wp,
    float* __restrict__ out)
{
    // A: [row][j] bf16, j<128 x-part, j>=128 d-part (updated per layer). 19200 B.
    // At the final epilogue A is dead; reused as Ct (48*64 fp32 = 12288 B).
    __shared__ __align__(16) unsigned short A[ROWS * ASTR];
    float* Ct = (float*)A;

    const int t  = threadIdx.x;
    const int b0 = blockIdx.x * SPB;

    // ---- stage d first (kept in registers for the residual): 8 samples x 384 floats = 1536 float2
    float2 dres[6];
    {
        const float2* d2 = (const float2*)(d + (size_t)b0 * (ND * NPAIR));
        #pragma unroll
        for (int m = 0; m < 6; ++m) dres[m] = d2[m * 256 + t];
    }
    // ---- stage x: 8 samples x 768 floats = 1536 float4; coalesced; convert + scatter to A x-part
    {
        const float4* x4 = (const float4*)(x + (size_t)b0 * (ND * 12));
        float4 v[6];
        #pragma unroll
        for (int m = 0; m < 6; ++m) v[m] = x4[m * 256 + t];
        unsigned* A32 = (unsigned*)A;
        #pragma unroll
        for (int m = 0; m < 6; ++m) {
            int idx = m * 256 + t;                // 0..1535
            int b   = idx / 192;                  // 192 float4 per sample
            int rem = idx - b * 192;
            int i   = rem / 3;                    // channel
            int c0  = (rem - i * 3) * 4;          // 0,4,8
            int row0 = b * 6 + (c0 >> 1);         // slot = c/2
            A32[row0 * (ASTR / 2) + i]       = f2bf2(v[m].x, v[m].y);  // j = 2i, 2i+1
            A32[(row0 + 1) * (ASTR / 2) + i] = f2bf2(v[m].z, v[m].w);
        }
    }
    // ---- scatter d to A d-part: each float2 = same i, slots (s,s+1)
    {
        #pragma unroll
        for (int m = 0; m < 6; ++m) {
            int idx = m * 256 + t;                // 0..1535
            int e   = idx * 2;
            int b   = e / 384;
            int rem = e - b * 384;
            int i   = rem / 6;
            int s   = rem - i * 6;                // even
            int row = b * 6 + s;
            A[row * ASTR + 128 + i]       = f2bf(dres[m].x);
            A[(row + 1) * ASTR + 128 + i] = f2bf(dres[m].y);
        }
    }
    __syncthreads();

    const int wave = t >> 6;
    const int lane = t & 63;
    const int l15  = lane & 15;
    const int quad = lane >> 4;
    const int nbase = wave * 16;                  // each wave: all 48 rows x 16 cols

    #pragma unroll
    for (int L = 0; L < 3; ++L) {
        const float* bL = (L == 0) ? b1 : (L == 1) ? b2 : b3;
        const unsigned short* WL = Wp + L * (64 * 192);

        // B fragments for this wave's 16 output cols: 6 k-steps, from L2-resident packed weights
        bf16x8 Bf[6];
        #pragma unroll
        for (int kk = 0; kk < 6; ++kk)
            Bf[kk] = *(const bf16x8*)(WL + (nbase + l15) * 192 + kk * 32 + quad * 8);
        float bias = bL[nbase + l15];

        floatx4 acc[3] = {};
        #pragma unroll
        for (int kk = 0; kk < 6; ++kk) {
            #pragma unroll
            for (int mt = 0; mt < 3; ++mt) {
                bf16x8 Af = *(const bf16x8*)(A + (mt * 16 + l15) * ASTR + kk * 32 + quad * 8);
                acc[mt] = __builtin_amdgcn_mfma_f32_16x16x32_bf16(Af, Bf[kk], acc[mt], 0, 0, 0);
            }
        }

        const int o = nbase + l15;
        if (L < 2) {
            __syncthreads();   // everyone done reading old d-part
            #pragma unroll
            for (int mt = 0; mt < 3; ++mt) {
                #pragma unroll
                for (int r = 0; r < 4; ++r) {
                    int row = mt * 16 + quad * 4 + r;   // C/D: col=lane&15, row=quad*4+reg
                    float v = acc[mt][r] + bias;
                    v = v > 0.f ? v : 0.f;
                    A[row * ASTR + 128 + o] = f2bf(v);
                }
            }
            __syncthreads();   // new d visible before next layer's reads
        } else {
            __syncthreads();   // all waves done reading A; safe to overlay Ct
            // transpose C (fp32, + bias) into [b][o*6+s] layout over A's storage
            #pragma unroll
            for (int mt = 0; mt < 3; ++mt) {
                #pragma unroll
                for (int r = 0; r < 4; ++r) {
                    int row = mt * 16 + quad * 4 + r;
                    int bl  = row / 6;
                    int s   = row - bl * 6;
                    Ct[bl * (ND * NPAIR) + o * NPAIR + s] = acc[mt][r] + bias;
                }
            }
            __syncthreads();
            // coalesced float2 stores fused with register-resident residual
            float2* out2 = (float2*)(out + (size_t)b0 * (ND * NPAIR));
            const float2* Ct2 = (const float2*)Ct;
            #pragma unroll
            for (int m = 0; m < 6; ++m) {
                int idx = m * 256 + t;
                float2 c = Ct2[idx];
                float2 r;
                r.x = c.x + dres[m].x; r.x = r.x > 0.f ? r.x : 0.f;
                r.y = c.y + dres[m].y; r.y = r.y > 0.f ? r.y : 0.f;
                out2[idx] = r;
            }
        }
    }
}

extern "C" void kernel_launch(void* const* d_in, const int* in_sizes, int n_in,
                              void* d_out, int out_size, void* d_ws, size_t ws_size,
                              hipStream_t stream)
{
    const float* x  = (const float*)d_in[0];
    const float* dd = (const float*)d_in[1];
    const float* W1 = (const float*)d_in[2];
    const float* b1 = (const float*)d_in[3];
    const float* W2 = (const float*)d_in[4];
    const float* b2 = (const float*)d_in[5];
    const float* W3 = (const float*)d_in[6];
    const float* b3 = (const float*)d_in[7];
    float* out = (float*)d_out;
    unsigned short* Wp = (unsigned short*)d_ws;   // 3*64*192*2 = 73728 B

    int n = in_sizes[0] / (ND * 12);              // 65536

    repack_w<<<144, 256, 0, stream>>>(W1, W2, W3, Wp);
    dijet_main<<<n / SPB, 256, 0, stream>>>(x, dd, b1, b2, b3, Wp, out);
}

// Round 7
// 386.913 us; speedup vs baseline: 2.3716x; 1.0095x over previous
//
#include <hip/hip_runtime.h>

#define ND 64
#define NPAIR 6

typedef short bf16x8 __attribute__((ext_vector_type(8)));
typedef float floatx4 __attribute__((ext_vector_type(4)));

static constexpr int SPB  = 16;            // samples per block (R7: 8 -> 16, single variable)
static constexpr int ROWS = SPB * NPAIR;   // 96 M-rows per block = 6 M-tiles
static constexpr int ASTR = 200;           // halfwords per A row (192 + 8 pad; 400B, 16B-aligned, bank-spread)

// Native bf16 conversion: compiler emits v_cvt_pk_bf16_f32 (RNE) for scalar casts on gfx950.
__device__ __forceinline__ unsigned short f2bf(float f) {
    __bf16 h = (__bf16)f;
    return __builtin_bit_cast(unsigned short, h);
}
__device__ __forceinline__ unsigned f2bf2(float lo, float hi) {
    return (unsigned)f2bf(lo) | ((unsigned)f2bf(hi) << 16);
}

// Repack W1..3 [o][i][k] fp32 -> bf16 B-operand layout P[L][n=o][j], j<128: (i=j>>1,k=j&1), j>=128: (i=j-128,k=2)
__global__ void repack_w(const float* __restrict__ W1, const float* __restrict__ W2,
                         const float* __restrict__ W3, unsigned short* __restrict__ P) {
    int idx = blockIdx.x * 256 + threadIdx.x;
    if (idx >= 3 * 64 * 192) return;
    int j = idx % 192;
    int n = (idx / 192) % 64;
    int L = idx / (192 * 64);
    const float* W = (L == 0) ? W1 : (L == 1) ? W2 : W3;
    float v = (j < 128) ? W[n * 192 + (j >> 1) * 3 + (j & 1)]
                        : W[n * 192 + (j - 128) * 3 + 2];
    P[idx] = f2bf(v);
}

__global__ __launch_bounds__(256, 4) void dijet_main(
    const float* __restrict__ x, const float* __restrict__ d,
    const float* __restrict__ b1, const float* __restrict__ b2,
    const float* __restrict__ b3, const unsigned short* __restrict__ Wp,
    float* __restrict__ out)
{
    // A: [row][j] bf16, j<128 x-part, j>=128 d-part (updated per layer). 38400 B.
    // At the final epilogue A is dead; reused as Ct (96*64 fp32 = 24576 B).
    __shared__ __align__(16) unsigned short A[ROWS * ASTR];
    float* Ct = (float*)A;

    const int t  = threadIdx.x;
    const int b0 = blockIdx.x * SPB;

    // ---- stage d first (kept in registers for the residual): 16 samples x 384 floats = 3072 float2
    float2 dres[12];
    {
        const float2* d2 = (const float2*)(d + (size_t)b0 * (ND * NPAIR));
        #pragma unroll
        for (int m = 0; m < 12; ++m) dres[m] = d2[m * 256 + t];
    }
    // ---- stage x: 16 samples x 768 floats = 3072 float4; coalesced; convert + scatter to A x-part
    {
        const float4* x4 = (const float4*)(x + (size_t)b0 * (ND * 12));
        float4 v[12];
        #pragma unroll
        for (int m = 0; m < 12; ++m) v[m] = x4[m * 256 + t];
        unsigned* A32 = (unsigned*)A;
        #pragma unroll
        for (int m = 0; m < 12; ++m) {
            int idx = m * 256 + t;                // 0..3071
            int b   = idx / 192;                  // 192 float4 per sample
            int rem = idx - b * 192;
            int i   = rem / 3;                    // channel
            int c0  = (rem - i * 3) * 4;          // 0,4,8
            int row0 = b * 6 + (c0 >> 1);         // slot = c/2
            A32[row0 * (ASTR / 2) + i]       = f2bf2(v[m].x, v[m].y);  // j = 2i, 2i+1
            A32[(row0 + 1) * (ASTR / 2) + i] = f2bf2(v[m].z, v[m].w);
        }
    }
    // ---- scatter d to A d-part: each float2 = same i, slots (s,s+1)
    {
        #pragma unroll
        for (int m = 0; m < 12; ++m) {
            int idx = m * 256 + t;                // 0..3071
            int e   = idx * 2;
            int b   = e / 384;
            int rem = e - b * 384;
            int i   = rem / 6;
            int s   = rem - i * 6;                // even
            int row = b * 6 + s;
            A[row * ASTR + 128 + i]       = f2bf(dres[m].x);
            A[(row + 1) * ASTR + 128 + i] = f2bf(dres[m].y);
        }
    }
    __syncthreads();

    const int wave = t >> 6;
    const int lane = t & 63;
    const int l15  = lane & 15;
    const int quad = lane >> 4;
    const int nbase = wave * 16;                  // each wave: all 96 rows x 16 cols

    #pragma unroll
    for (int L = 0; L < 3; ++L) {
        const float* bL = (L == 0) ? b1 : (L == 1) ? b2 : b3;
        const unsigned short* WL = Wp + L * (64 * 192);

        // B fragments for this wave's 16 output cols: 6 k-steps, from L2-resident packed weights
        bf16x8 Bf[6];
        #pragma unroll
        for (int kk = 0; kk < 6; ++kk)
            Bf[kk] = *(const bf16x8*)(WL + (nbase + l15) * 192 + kk * 32 + quad * 8);
        float bias = bL[nbase + l15];

        floatx4 acc[6] = {};
        #pragma unroll
        for (int kk = 0; kk < 6; ++kk) {
            #pragma unroll
            for (int mt = 0; mt < 6; ++mt) {
                bf16x8 Af = *(const bf16x8*)(A + (mt * 16 + l15) * ASTR + kk * 32 + quad * 8);
                acc[mt] = __builtin_amdgcn_mfma_f32_16x16x32_bf16(Af, Bf[kk], acc[mt], 0, 0, 0);
            }
        }

        const int o = nbase + l15;
        if (L < 2) {
            __syncthreads();   // everyone done reading old d-part
            #pragma unroll
            for (int mt = 0; mt < 6; ++mt) {
                #pragma unroll
                for (int r = 0; r < 4; ++r) {
                    int row = mt * 16 + quad * 4 + r;   // C/D: col=lane&15, row=quad*4+reg
                    float v = acc[mt][r] + bias;
                    v = v > 0.f ? v : 0.f;
                    A[row * ASTR + 128 + o] = f2bf(v);
                }
            }
            __syncthreads();   // new d visible before next layer's reads
        } else {
            __syncthreads();   // all waves done reading A; safe to overlay Ct
            // transpose C (fp32, + bias) into [b][o*6+s] layout over A's storage
            #pragma unroll
            for (int mt = 0; mt < 6; ++mt) {
                #pragma unroll
                for (int r = 0; r < 4; ++r) {
                    int row = mt * 16 + quad * 4 + r;
                    int bl  = row / 6;
                    int s   = row - bl * 6;
                    Ct[bl * (ND * NPAIR) + o * NPAIR + s] = acc[mt][r] + bias;
                }
            }
            __syncthreads();
            // coalesced float2 stores fused with register-resident residual
            float2* out2 = (float2*)(out + (size_t)b0 * (ND * NPAIR));
            const float2* Ct2 = (const float2*)Ct;
            #pragma unroll
            for (int m = 0; m < 12; ++m) {
                int idx = m * 256 + t;
                float2 c = Ct2[idx];
                float2 r;
                r.x = c.x + dres[m].x; r.x = r.x > 0.f ? r.x : 0.f;
                r.y = c.y + dres[m].y; r.y = r.y > 0.f ? r.y : 0.f;
                out2[idx] = r;
            }
        }
    }
}

extern "C" void kernel_launch(void* const* d_in, const int* in_sizes, int n_in,
                              void* d_out, int out_size, void* d_ws, size_t ws_size,
                              hipStream_t stream)
{
    const float* x  = (const float*)d_in[0];
    const float* dd = (const float*)d_in[1];
    const float* W1 = (const float*)d_in[2];
    const float* b1 = (const float*)d_in[3];
    const float* W2 = (const float*)d_in[4];
    const float* b2 = (const float*)d_in[5];
    const float* W3 = (const float*)d_in[6];
    const float* b3 = (const float*)d_in[7];
    float* out = (float*)d_out;
    unsigned short* Wp = (unsigned short*)d_ws;   // 3*64*192*2 = 73728 B

    int n = in_sizes[0] / (ND * 12);              // 65536

    repack_w<<<144, 256, 0, stream>>>(W1, W2, W3, Wp);
    dijet_main<<<n / SPB, 256, 0, stream>>>(x, dd, b1, b2, b3, Wp, out);
}